// Round 7
// baseline (117.351 us; speedup 1.0000x reference)
//
#include <hip/hip_runtime.h>

#define PY 7
#define PX 7
#define PZ 3
#define S_BINS 147          // 7*7*3
#define C_CH   48
#define PER_ROI 7056        // 48*147
#define CPT    12           // channels per block
#define NCHUNK 4
#define OUT_PER_BLK (CPT * S_BINS)   // 1764
#define LDS_FLOATS 16128    // 63 KB

// One block per (roi, 12-channel chunk). Stage footprint -> LDS, compute from LDS.
__global__ __launch_bounds__(256) void roialign3d_kernel(
    const float* __restrict__ f0, const float* __restrict__ f1,
    const float* __restrict__ f2, const float* __restrict__ f3,
    const float* __restrict__ rois, float* __restrict__ out)
{
    __shared__ float lds[LDS_FLOATS];

    const int bid = blockIdx.x;
    const int n   = bid >> 2;          // roi
    const int cs  = bid & 3;           // channel chunk
    const int tid = threadIdx.x;

    // ---- uniform roi setup (all threads redundantly; block-uniform) ----
    const float* r = rois + n * 7;
    float by1 = r[0], bx1 = r[1], by2 = r[2], bx2 = r[3], bz1 = r[4], bz2 = r[5];
    int b = (int)r[6];

    float h = by2 - by1, w = bx2 - bx1;
    float lv = rintf(4.0f + 0.5f * log2f(h * w));
    lv = fminf(fmaxf(lv, 0.0f), 3.0f);
    int level = (int)lv;

    const float* fm; int Y, X, Z;
    switch (level) {
        case 0: fm = f0; Y = 96; X = 96; Z = 48; break;
        case 1: fm = f1; Y = 48; X = 48; Z = 24; break;
        case 2: fm = f2; Y = 24; X = 24; Z = 12; break;
        default: fm = f3; Y = 12; X = 12; Z = 6;  break;
    }
    const int plane = Y * X * Z;
    const float* base = fm + ((size_t)b * C_CH + cs * CPT) * (size_t)plane;

    float fy1 = by1 * Y, bwy = (by2 * Y - fy1) * (1.0f / PY);
    float fx1 = bx1 * X, bwx = (bx2 * X - fx1) * (1.0f / PX);
    float fz1 = bz1 * Z, bwz = (bz2 * Z - fz1) * (1.0f / PZ);

    // footprint bounds (monotone bin centers -> use first/last bins)
    float yc0 = fminf(fmaxf(fy1 + 0.5f * bwy, 0.0f), (float)(Y - 1));
    float yc6 = fminf(fmaxf(fy1 + 6.5f * bwy, 0.0f), (float)(Y - 1));
    int ymin = (int)floorf(yc0);
    int ymax = min((int)floorf(yc6) + 1, Y - 1);
    int NY = ymax - ymin + 1;

    float xc0 = fminf(fmaxf(fx1 + 0.5f * bwx, 0.0f), (float)(X - 1));
    float xc6 = fminf(fmaxf(fx1 + 6.5f * bwx, 0.0f), (float)(X - 1));
    int xmin = (int)floorf(xc0);
    int xmax = min((int)floorf(xc6) + 1, X - 1);
    int NX = xmax - xmin + 1;

    float zc0 = fminf(fmaxf(fz1 + 0.5f * bwz, 0.0f), (float)(Z - 1));
    float zc2 = fminf(fmaxf(fz1 + 2.5f * bwz, 0.0f), (float)(Z - 1));
    int zmin = min((int)floorf(zc0), Z - 2);
    int zmax = min((int)floorf(zc2), Z - 2) + 1;
    int NZ = zmax - zmin + 1;               // >= 2

    int shift = 32 - __clz(NZ - 1);         // RS = pow2 >= NZ
    int RS    = 1 << shift;
    int lgXP  = (NX > 1) ? (32 - __clz(NX - 1)) : 0;
    int XP    = 1 << lgXP;
    int per_ch = (NY << lgXP) << shift;     // NY*XP*RS
    bool use_lds = (CPT * per_ch) <= LDS_FLOATS;

    // ---- stage footprint (coalesced, contiguous z-runs) ----
    if (use_lds) {
        for (int ch = 0; ch < CPT; ++ch) {
            const float* chb = base + (size_t)ch * plane;
            float* ldch = lds + ch * per_ch;
            for (int j = tid; j < per_ch; j += 256) {
                int yy = j >> (shift + lgXP);
                int xx = (j >> shift) & (XP - 1);
                int dz = j & (RS - 1);
                if (xx < NX && dz < NZ)
                    ldch[j] = chb[((ymin + yy) * X + (xmin + xx)) * Z + zmin + dz];
            }
        }
        __syncthreads();
    }

    // ---- compute 1764 outputs ----
    float* outp = out + (size_t)n * PER_ROI + (size_t)cs * OUT_PER_BLK;
    float Yf = (float)Y, Xf = (float)X, Zf = (float)Z;

    for (int oi = tid; oi < OUT_PER_BLK; oi += 256) {
        unsigned c = (unsigned)oi / 147u;
        unsigned s = (unsigned)oi - c * 147u;
        int ybin = s / 21;
        int t2   = s - ybin * 21;
        int xbin = t2 / 3;
        int zbin = t2 - xbin * 3;

        float yy = fy1 + (ybin + 0.5f) * bwy;
        float xx = fx1 + (xbin + 0.5f) * bwx;
        float zz = fz1 + (zbin + 0.5f) * bwz;

        bool valid = (yy > -1.0f) && (yy < Yf) &&
                     (xx > -1.0f) && (xx < Xf) &&
                     (zz > -1.0f) && (zz < Zf);

        float ycl = fminf(fmaxf(yy, 0.0f), Yf - 1.0f);
        float xcl = fminf(fmaxf(xx, 0.0f), Xf - 1.0f);
        float zcl = fminf(fmaxf(zz, 0.0f), Zf - 1.0f);

        int y0 = (int)floorf(ycl);
        int x0 = (int)floorf(xcl);
        int z0 = (int)floorf(zcl);
        int y1i = min(y0 + 1, Y - 1);
        int x1i = min(x0 + 1, X - 1);

        float ly = ycl - (float)y0, lx = xcl - (float)x0, lz = zcl - (float)z0;
        float hy = 1.0f - ly,       hx = 1.0f - lx,       hz = 1.0f - lz;

        int  zb    = min(z0, Z - 2);
        bool sh    = (zb != z0);
        float wlo  = sh ? 0.0f : hz;
        float whi  = sh ? 1.0f : lz;
        if (!valid) { wlo = 0.0f; whi = 0.0f; }

        float w00 = hy * hx, w01 = hy * lx, w10 = ly * hx, w11 = ly * lx;

        float val;
        if (use_lds) {
            int ry0 = y0  - ymin, ry1 = y1i - ymin;
            int rx0 = x0  - xmin, rx1 = x1i - xmin;
            int rz  = zb  - zmin;
            int cNY = (int)c * NY;
            int i00 = ((((cNY + ry0) << lgXP) + rx0) << shift) + rz;
            int i01 = ((((cNY + ry0) << lgXP) + rx1) << shift) + rz;
            int i10 = ((((cNY + ry1) << lgXP) + rx0) << shift) + rz;
            int i11 = ((((cNY + ry1) << lgXP) + rx1) << shift) + rz;
            float lo = w00 * lds[i00]     + w01 * lds[i01]     + w10 * lds[i10]     + w11 * lds[i11];
            float hi = w00 * lds[i00 + 1] + w01 * lds[i01 + 1] + w10 * lds[i10 + 1] + w11 * lds[i11 + 1];
            val = wlo * lo + whi * hi;
        } else {
            const float* p = base + (size_t)c * plane;
            const float2 v00 = *(const float2*)(p + (y0  * X + x0 ) * Z + zb);
            const float2 v01 = *(const float2*)(p + (y0  * X + x1i) * Z + zb);
            const float2 v10 = *(const float2*)(p + (y1i * X + x0 ) * Z + zb);
            const float2 v11 = *(const float2*)(p + (y1i * X + x1i) * Z + zb);
            float lo = w00 * v00.x + w01 * v01.x + w10 * v10.x + w11 * v11.x;
            float hi = w00 * v00.y + w01 * v01.y + w10 * v10.y + w11 * v11.y;
            val = wlo * lo + whi * hi;
        }

        __builtin_nontemporal_store(val, &outp[oi]);
    }
}

extern "C" void kernel_launch(void* const* d_in, const int* in_sizes, int n_in,
                              void* d_out, int out_size, void* d_ws, size_t ws_size,
                              hipStream_t stream) {
    const float* f0   = (const float*)d_in[0];
    const float* f1   = (const float*)d_in[1];
    const float* f2   = (const float*)d_in[2];
    const float* f3   = (const float*)d_in[3];
    const float* rois = (const float*)d_in[4];
    float* out = (float*)d_out;

    int n_rois = out_size / PER_ROI;     // 1200
    int grid   = n_rois * NCHUNK;        // 4800 blocks
    roialign3d_kernel<<<grid, 256, 0, stream>>>(f0, f1, f2, f3, rois, out);
}

// Round 8
// 64.550 us; speedup vs baseline: 1.8180x; 1.8180x over previous
//
#include <hip/hip_runtime.h>

#define PY 7
#define PX 7
#define PZ 3
#define S_BINS 147          // 7*7*3
#define C_CH   48
#define PER_ROI 7056        // 48*147
#define CPB    12           // channels per block
#define NCHUNK 4
#define OUT_PER_BLK (CPB * S_BINS)   // 1764
#define LDS_FLOATS 10240    // 40 KB -> 4 blocks/CU

__global__ __launch_bounds__(256) void roialign3d_kernel(
    const float* __restrict__ f0, const float* __restrict__ f1,
    const float* __restrict__ f2, const float* __restrict__ f3,
    const float* __restrict__ rois, float* __restrict__ out)
{
    __shared__ float lds[LDS_FLOATS];

    const int bid = blockIdx.x;
    const int n   = bid >> 2;          // roi
    const int cs  = bid & 3;           // channel chunk
    const int tid = threadIdx.x;

    // ---- uniform roi setup ----
    const float* r = rois + n * 7;
    float by1 = r[0], bx1 = r[1], by2 = r[2], bx2 = r[3], bz1 = r[4], bz2 = r[5];
    int b = (int)r[6];

    float h = by2 - by1, w = bx2 - bx1;
    float lv = rintf(4.0f + 0.5f * log2f(h * w));
    lv = fminf(fmaxf(lv, 0.0f), 3.0f);
    int level = (int)lv;

    const float* fm; int Y, X, Z;
    switch (level) {
        case 0: fm = f0; Y = 96; X = 96; Z = 48; break;
        case 1: fm = f1; Y = 48; X = 48; Z = 24; break;
        case 2: fm = f2; Y = 24; X = 24; Z = 12; break;
        default: fm = f3; Y = 12; X = 12; Z = 6;  break;
    }
    const int plane = Y * X * Z;
    const float* base = fm + ((size_t)b * C_CH + cs * CPB) * (size_t)plane;

    float fy1 = by1 * Y, bwy = (by2 * Y - fy1) * (1.0f / PY);
    float fx1 = bx1 * X, bwx = (bx2 * X - fx1) * (1.0f / PX);
    float fz1 = bz1 * Z, bwz = (bz2 * Z - fz1) * (1.0f / PZ);
    float Yf = (float)Y, Xf = (float)X, Zf = (float)Z;

    // footprint bounds (bin centers are monotone in bin index)
    float yc0 = fminf(fmaxf(fy1 + 0.5f * bwy, 0.0f), Yf - 1.0f);
    float yc6 = fminf(fmaxf(fy1 + 6.5f * bwy, 0.0f), Yf - 1.0f);
    int ymin = (int)floorf(yc0);
    int ymax = min((int)floorf(yc6) + 1, Y - 1);
    int NY = ymax - ymin + 1;

    float xc0 = fminf(fmaxf(fx1 + 0.5f * bwx, 0.0f), Xf - 1.0f);
    float xc6 = fminf(fmaxf(fx1 + 6.5f * bwx, 0.0f), Xf - 1.0f);
    int xmin = (int)floorf(xc0);
    int xmax = min((int)floorf(xc6) + 1, X - 1);
    int NX = xmax - xmin + 1;

    float zc0 = fminf(fmaxf(fz1 + 0.5f * bwz, 0.0f), Zf - 1.0f);
    float zc2 = fminf(fmaxf(fz1 + 2.5f * bwz, 0.0f), Zf - 1.0f);
    int zmin = min((int)floorf(zc0), Z - 2);
    int zb2  = min((int)floorf(zc2), Z - 2);
    int zcov = zb2 + 2 - zmin;              // staged z extent, >= 2

    int lgz = 32 - __clz(zcov - 1);         // NZP = pow2 >= zcov
    int lgx = (NX > 1) ? (32 - __clz(NX - 1)) : 0;
    int NZP = 1 << lgz;
    int per_ch = NY << (lgx + lgz);
    bool staged = (CPB * per_ch) <= LDS_FLOATS;

    if (staged) {
        // ---- stage tight footprint, scalar predicated (lanes contiguous) ----
        int xzm = (1 << (lgx + lgz)) - 1;
        for (int ch = 0; ch < CPB; ++ch) {
            const float* cb = base + (size_t)ch * plane;
            float* lch = lds + ch * per_ch;
            for (int j = tid; j < per_ch; j += 256) {
                int yy  = j >> (lgx + lgz);
                int rem = j & xzm;
                int xx  = rem >> lgz;
                int gz  = zmin + (rem & (NZP - 1));
                if (xx < NX && gz < Z)
                    lch[j] = cb[((ymin + yy) * X + (xmin + xx)) * Z + gz];
            }
        }
        __syncthreads();
    }

    float* outp = out + (size_t)n * PER_ROI + (size_t)cs * OUT_PER_BLK;

    for (int oi = tid; oi < OUT_PER_BLK; oi += 256) {
        unsigned c = (unsigned)oi / 147u;
        unsigned s = (unsigned)oi - c * 147u;
        int ybin = s / 21;
        int t2   = s - ybin * 21;
        int xbin = t2 / 3;
        int zbin = t2 - xbin * 3;

        float yy = fy1 + (ybin + 0.5f) * bwy;
        float xx = fx1 + (xbin + 0.5f) * bwx;
        float zz = fz1 + (zbin + 0.5f) * bwz;

        bool valid = (yy > -1.0f) && (yy < Yf) &&
                     (xx > -1.0f) && (xx < Xf) &&
                     (zz > -1.0f) && (zz < Zf);

        float ycl = fminf(fmaxf(yy, 0.0f), Yf - 1.0f);
        float xcl = fminf(fmaxf(xx, 0.0f), Xf - 1.0f);
        float zcl = fminf(fmaxf(zz, 0.0f), Zf - 1.0f);

        int y0 = (int)floorf(ycl);
        int x0 = (int)floorf(xcl);
        int z0 = (int)floorf(zcl);
        int y1i = min(y0 + 1, Y - 1);
        int x1i = min(x0 + 1, X - 1);

        float ly = ycl - (float)y0, lx = xcl - (float)x0, lz = zcl - (float)z0;
        float hy = 1.0f - ly,       hx = 1.0f - lx,       hz = 1.0f - lz;

        int  zb   = min(z0, Z - 2);
        bool sh   = (zb != z0);
        float wlo = sh ? 0.0f : hz;
        float whi = sh ? 1.0f : lz;
        if (!valid) { wlo = 0.0f; whi = 0.0f; }

        float w00 = hy * hx, w01 = hy * lx, w10 = ly * hx, w11 = ly * lx;

        float val;
        if (staged) {
            int ry0 = y0  - ymin, ry1 = y1i - ymin;
            int rx0 = x0  - xmin, rx1 = x1i - xmin;
            int dz  = zb  - zmin;
            const float* lc = lds + c * per_ch;
            int i00 = (((ry0 << lgx) + rx0) << lgz) + dz;
            int i01 = (((ry0 << lgx) + rx1) << lgz) + dz;
            int i10 = (((ry1 << lgx) + rx0) << lgz) + dz;
            int i11 = (((ry1 << lgx) + rx1) << lgz) + dz;
            float lo = w00 * lc[i00]     + w01 * lc[i01]     + w10 * lc[i10]     + w11 * lc[i11];
            float hi = w00 * lc[i00 + 1] + w01 * lc[i01 + 1] + w10 * lc[i10 + 1] + w11 * lc[i11 + 1];
            val = wlo * lo + whi * hi;
        } else {
            const float* p = base + (size_t)c * plane;
            const float2 v00 = *(const float2*)(p + (y0  * X + x0 ) * Z + zb);
            const float2 v01 = *(const float2*)(p + (y0  * X + x1i) * Z + zb);
            const float2 v10 = *(const float2*)(p + (y1i * X + x0 ) * Z + zb);
            const float2 v11 = *(const float2*)(p + (y1i * X + x1i) * Z + zb);
            float lo = w00 * v00.x + w01 * v01.x + w10 * v10.x + w11 * v11.x;
            float hi = w00 * v00.y + w01 * v01.y + w10 * v10.y + w11 * v11.y;
            val = wlo * lo + whi * hi;
        }

        __builtin_nontemporal_store(val, &outp[oi]);
    }
}

extern "C" void kernel_launch(void* const* d_in, const int* in_sizes, int n_in,
                              void* d_out, int out_size, void* d_ws, size_t ws_size,
                              hipStream_t stream) {
    const float* f0   = (const float*)d_in[0];
    const float* f1   = (const float*)d_in[1];
    const float* f2   = (const float*)d_in[2];
    const float* f3   = (const float*)d_in[3];
    const float* rois = (const float*)d_in[4];
    float* out = (float*)d_out;

    int n_rois = out_size / PER_ROI;     // 1200
    int grid   = n_rois * NCHUNK;        // 4800 blocks
    roialign3d_kernel<<<grid, 256, 0, stream>>>(f0, f1, f2, f3, rois, out);
}

// Round 9
// 39.613 us; speedup vs baseline: 2.9624x; 1.6295x over previous
//
#include <hip/hip_runtime.h>

#define PY 7
#define PX 7
#define PZ 3
#define S_BINS 147      // 7*7*3
#define C_CH   48
#define PER_ROI 7056    // 48*147
#define TPR    294      // 2 lanes (x-corners) per bin

// Two lanes per (roi, bin): lane cx loads x-corner cx rows; pair combined
// with one shfl_xor. Halves distinct-line visits vs 4-corner-per-lane (R4).
__global__ __launch_bounds__(256) void roialign3d_kernel(
    const float* __restrict__ f0, const float* __restrict__ f1,
    const float* __restrict__ f2, const float* __restrict__ f3,
    const float* __restrict__ rois, float* __restrict__ out, int total)
{
    int t = blockIdx.x * blockDim.x + threadIdx.x;
    if (t >= total) return;

    unsigned n   = (unsigned)t / TPR;
    unsigned rem = (unsigned)t - n * TPR;
    unsigned s   = rem >> 1;          // bin 0..146
    unsigned cx  = rem & 1;           // x-corner select

    const float* r = rois + n * 7;
    float by1 = r[0], bx1 = r[1], by2 = r[2], bx2 = r[3], bz1 = r[4], bz2 = r[5];
    int b = (int)r[6];

    // level from normalized h,w; jnp.round = round-half-even = rintf
    float h = by2 - by1, w = bx2 - bx1;
    float lv = rintf(4.0f + 0.5f * log2f(h * w));
    lv = fminf(fmaxf(lv, 0.0f), 3.0f);
    int level = (int)lv;

    const float* fm; int Y, X, Z;
    switch (level) {
        case 0: fm = f0; Y = 96; X = 96; Z = 48; break;
        case 1: fm = f1; Y = 48; X = 48; Z = 24; break;
        case 2: fm = f2; Y = 24; X = 24; Z = 12; break;
        default: fm = f3; Y = 12; X = 12; Z = 6;  break;
    }

    int ybin = s / (PX * PZ);
    int rs   = s - ybin * (PX * PZ);
    int xbin = rs / PZ;
    int zbin = rs - xbin * PZ;

    float fy1 = by1 * Y, fy2 = by2 * Y;
    float fx1 = bx1 * X, fx2 = bx2 * X;
    float fz1 = bz1 * Z, fz2 = bz2 * Z;

    float yy = fy1 + (ybin + 0.5f) * (fy2 - fy1) * (1.0f / PY);
    float xx = fx1 + (xbin + 0.5f) * (fx2 - fx1) * (1.0f / PX);
    float zz = fz1 + (zbin + 0.5f) * (fz2 - fz1) * (1.0f / PZ);

    bool valid = (yy > -1.0f) && (yy < (float)Y) &&
                 (xx > -1.0f) && (xx < (float)X) &&
                 (zz > -1.0f) && (zz < (float)Z);

    float yc = fminf(fmaxf(yy, 0.0f), (float)(Y - 1));
    float xc = fminf(fmaxf(xx, 0.0f), (float)(X - 1));
    float zc = fminf(fmaxf(zz, 0.0f), (float)(Z - 1));

    int y0 = (int)floorf(yc);
    int x0 = (int)floorf(xc);
    int z0 = (int)floorf(zc);
    int y1i = min(y0 + 1, Y - 1);
    int x1i = min(x0 + 1, X - 1);

    float ly = yc - (float)y0, lx = xc - (float)x0, lz = zc - (float)z0;
    float hy = 1.0f - ly,      hx = 1.0f - lx,      hz = 1.0f - lz;

    // z-pair base covering (zb, zb+1); clamp edge -> weights (0,1)
    int  zb    = min(z0, Z - 2);
    bool shift = (zb != z0);
    float wlo  = shift ? 0.0f : hz;
    float whi  = shift ? 1.0f : lz;
    if (!valid) { wlo = 0.0f; whi = 0.0f; }

    // this lane's x-corner and weights
    int   xcr = cx ? x1i : x0;
    float wx  = cx ? lx  : hx;
    float wA  = hy * wx;              // (y0, x_cx)
    float wB  = ly * wx;              // (y1, x_cx)

    const int plane = Y * X * Z;
    const float* base = fm + (size_t)b * C_CH * plane;

    const float* p0 = base + (y0  * X + xcr) * Z + zb;
    const float* p1 = base + (y1i * X + xcr) * Z + zb;

    float* op = out + (size_t)n * PER_ROI + s;

    #pragma unroll 8
    for (int c = 0; c < C_CH; ++c) {
        float2 va = *(const float2*)p0;
        float2 vb = *(const float2*)p1;

        float plo = wA * va.x + wB * vb.x;
        float phi = wA * va.y + wB * vb.y;

        // combine x0/x1 partials across the lane pair (DPP quad_perm)
        float qlo = __shfl_xor(plo, 1, 64);
        float qhi = __shfl_xor(phi, 1, 64);

        float lo = plo + qlo;
        float hi = phi + qhi;
        float val = wlo * lo + whi * hi;

        if (cx == 0) __builtin_nontemporal_store(val, op);

        p0 += plane; p1 += plane;
        op += S_BINS;
    }
}

extern "C" void kernel_launch(void* const* d_in, const int* in_sizes, int n_in,
                              void* d_out, int out_size, void* d_ws, size_t ws_size,
                              hipStream_t stream) {
    const float* f0   = (const float*)d_in[0];
    const float* f1   = (const float*)d_in[1];
    const float* f2   = (const float*)d_in[2];
    const float* f3   = (const float*)d_in[3];
    const float* rois = (const float*)d_in[4];
    float* out = (float*)d_out;

    int n_rois = out_size / PER_ROI;     // 1200
    int total  = n_rois * TPR;           // 352800
    int block  = 256;
    int grid   = (total + block - 1) / block;
    roialign3d_kernel<<<grid, block, 0, stream>>>(f0, f1, f2, f3, rois, out, total);
}

// Round 10
// 35.772 us; speedup vs baseline: 3.2805x; 1.1074x over previous
//
#include <hip/hip_runtime.h>

#define PY 7
#define PX 7
#define PZ 3
#define S_BINS 147      // 7*7*3
#define C_CH   48
#define PER_ROI 7056    // 48*147

// One thread per (roi, bin); loops over 48 channels with geometry in registers.
// R4 structure: empirically optimal. Lane mapping keeps 3 z-bins of each (y,x)
// on adjacent lanes (cache-line sharing within each gather instruction);
// float2 z-pair loads halve gather instructions; NT stores keep L2/L3 for fmaps.
__global__ __launch_bounds__(256) void roialign3d_kernel(
    const float* __restrict__ f0, const float* __restrict__ f1,
    const float* __restrict__ f2, const float* __restrict__ f3,
    const float* __restrict__ rois, float* __restrict__ out, int total_bins)
{
    int t = blockIdx.x * blockDim.x + threadIdx.x;
    if (t >= total_bins) return;

    unsigned n = (unsigned)t / S_BINS;
    unsigned s = (unsigned)t - n * S_BINS;

    const float* r = rois + n * 7;
    float by1 = r[0], bx1 = r[1], by2 = r[2], bx2 = r[3], bz1 = r[4], bz2 = r[5];
    int b = (int)r[6];

    // level from normalized h,w; jnp.round = round-half-even = rintf
    float h = by2 - by1, w = bx2 - bx1;
    float lv = rintf(4.0f + 0.5f * log2f(h * w));
    lv = fminf(fmaxf(lv, 0.0f), 3.0f);
    int level = (int)lv;

    const float* fm; int Y, X, Z;
    switch (level) {
        case 0: fm = f0; Y = 96; X = 96; Z = 48; break;
        case 1: fm = f1; Y = 48; X = 48; Z = 24; break;
        case 2: fm = f2; Y = 24; X = 24; Z = 12; break;
        default: fm = f3; Y = 12; X = 12; Z = 6;  break;
    }

    int ybin = s / (PX * PZ);
    int rs   = s - ybin * (PX * PZ);
    int xbin = rs / PZ;
    int zbin = rs - xbin * PZ;

    float fy1 = by1 * Y, fy2 = by2 * Y;
    float fx1 = bx1 * X, fx2 = bx2 * X;
    float fz1 = bz1 * Z, fz2 = bz2 * Z;

    float yy = fy1 + (ybin + 0.5f) * (fy2 - fy1) * (1.0f / PY);
    float xx = fx1 + (xbin + 0.5f) * (fx2 - fx1) * (1.0f / PX);
    float zz = fz1 + (zbin + 0.5f) * (fz2 - fz1) * (1.0f / PZ);

    bool valid = (yy > -1.0f) && (yy < (float)Y) &&
                 (xx > -1.0f) && (xx < (float)X) &&
                 (zz > -1.0f) && (zz < (float)Z);

    float yc = fminf(fmaxf(yy, 0.0f), (float)(Y - 1));
    float xc = fminf(fmaxf(xx, 0.0f), (float)(X - 1));
    float zc = fminf(fmaxf(zz, 0.0f), (float)(Z - 1));

    int y0 = (int)floorf(yc);
    int x0 = (int)floorf(xc);
    int z0 = (int)floorf(zc);
    int y1i = min(y0 + 1, Y - 1);
    int x1i = min(x0 + 1, X - 1);

    float ly = yc - (float)y0, lx = xc - (float)x0, lz = zc - (float)z0;
    float hy = 1.0f - ly,      hx = 1.0f - lx,      hz = 1.0f - lz;

    // z-pair base covering (zb, zb+1); clamp edge -> weights (0,1)
    int  zb    = min(z0, Z - 2);
    bool shift = (zb != z0);
    float wlo  = shift ? 0.0f : hz;
    float whi  = shift ? 1.0f : lz;
    if (!valid) { wlo = 0.0f; whi = 0.0f; }

    float w00 = hy * hx, w01 = hy * lx, w10 = ly * hx, w11 = ly * lx;

    const int plane = Y * X * Z;
    const float* base = fm + (size_t)b * C_CH * plane;

    const float* p00 = base + (y0  * X + x0 ) * Z + zb;
    const float* p01 = base + (y0  * X + x1i) * Z + zb;
    const float* p10 = base + (y1i * X + x0 ) * Z + zb;
    const float* p11 = base + (y1i * X + x1i) * Z + zb;

    float* op = out + (size_t)n * PER_ROI + s;

    #pragma unroll 4
    for (int c = 0; c < C_CH; ++c) {
        float2 v00 = *(const float2*)p00;
        float2 v01 = *(const float2*)p01;
        float2 v10 = *(const float2*)p10;
        float2 v11 = *(const float2*)p11;

        float lo = w00 * v00.x + w01 * v01.x + w10 * v10.x + w11 * v11.x;
        float hi = w00 * v00.y + w01 * v01.y + w10 * v10.y + w11 * v11.y;
        float val = wlo * lo + whi * hi;

        __builtin_nontemporal_store(val, op);

        p00 += plane; p01 += plane; p10 += plane; p11 += plane;
        op += S_BINS;
    }
}

extern "C" void kernel_launch(void* const* d_in, const int* in_sizes, int n_in,
                              void* d_out, int out_size, void* d_ws, size_t ws_size,
                              hipStream_t stream) {
    const float* f0   = (const float*)d_in[0];
    const float* f1   = (const float*)d_in[1];
    const float* f2   = (const float*)d_in[2];
    const float* f3   = (const float*)d_in[3];
    const float* rois = (const float*)d_in[4];
    float* out = (float*)d_out;

    int n_rois = out_size / PER_ROI;        // 1200
    int total_bins = n_rois * S_BINS;       // 176400
    int block = 256;
    int grid  = (total_bins + block - 1) / block;
    roialign3d_kernel<<<grid, block, 0, stream>>>(f0, f1, f2, f3, rois, out, total_bins);
}